// Round 5
// baseline (290.432 us; speedup 1.0000x reference)
//
#include <hip/hip_runtime.h>
#include <hip/hip_bf16.h>
#include <hip/hip_fp16.h>

// SpatialAttention: B=32, C=273, T=3000, O=270, D=2048. fp32 in, fp32 out.
#define NB 32
#define NC 273
#define NT 3000
#define NO 270
#define ND 2048
#define CP 288  // C padded to 9*32 for out-GEMM K dimension

typedef _Float16 f16x8 __attribute__((ext_vector_type(8)));
typedef float f32x4 __attribute__((ext_vector_type(4)));

// Workspace layout (bytes):
//   [55296000, 64,730,880)  scores float   [NB][NO][NC]
//   [64730880, 69,707,520)  W     _Float16 [NB][NO][CP]  (softmaxed weights, zero-padded)
//   [69707520, 70,813,440)  headsh _Float16 [NO][ND]
#define S_OFF 55296000UL
#define W_OFF 64730880UL
#define H_OFF 69707520UL

__device__ __forceinline__ unsigned short f2h_bits(float f) {
  _Float16 h = (_Float16)f;
  unsigned short u;
  __builtin_memcpy(&u, &h, 2);
  return u;
}

// ---------------------------------------------------------------------------
// heads fp32 -> fp16. 270 blocks x 256 thr x 8 elems (exact).
// ---------------------------------------------------------------------------
__global__ void heads_cvt_kernel(const float* __restrict__ heads,
                                 _Float16* __restrict__ hh) {
  const size_t idx = ((size_t)blockIdx.x * 256 + threadIdx.x) * 8;
  const float4 a = *reinterpret_cast<const float4*>(heads + idx);
  const float4 c = *reinterpret_cast<const float4*>(heads + idx + 4);
  f16x8 v;
  v[0] = (_Float16)a.x; v[1] = (_Float16)a.y; v[2] = (_Float16)a.z; v[3] = (_Float16)a.w;
  v[4] = (_Float16)c.x; v[5] = (_Float16)c.y; v[6] = (_Float16)c.z; v[7] = (_Float16)c.w;
  *reinterpret_cast<f16x8*>(hh + idx) = v;
}

// ---------------------------------------------------------------------------
// scores[b,o,c] = sum_d heads[o,d]*emb[b,c,d], with the emb B-tile GENERATED
// in-register (phase naturally in revolutions -> fract + v_sin; cos folded
// as +0.25 rev). Tile 64(o) x 64(c), K-step 64, 4 waves 2x2.
// grid = 800 (5 c-tiles x 5 o-tiles x 32 b)
// ---------------------------------------------------------------------------
__global__ void scores_kernel(const _Float16* __restrict__ hh,
                              const float* __restrict__ layout,
                              float* __restrict__ scores) {
  __shared__ _Float16 As[64][72];
  __shared__ _Float16 Bs[64][72];
  const int gid = blockIdx.x;
  const int tid = threadIdx.x;
  const int b = gid / 25;
  const int rem = gid % 25;
  const int o0 = (rem / 5) * 64;
  const int c0 = (rem % 5) * 64;
  const int lane = tid & 63, w = tid >> 6;
  const int wm = (w >> 1) * 32, wn = (w & 1) * 32;
  const int ln = lane & 15, quad = lane >> 4;
  const int sr = tid >> 2;        // staging row 0..63 (o for A, c for B)
  const int sk = (tid & 3) * 16;  // k-chunk offset (halves)

  // Per-thread channel position for B-tile generation.
  const int ch = c0 + sr;
  float px = 0.f, py = 0.f;
  if (ch < NC) {
    const float inv = 1.0f / 1.2f;
    const float* lp = layout + ((size_t)b * NC + ch) * 2;
    px = (lp[0] + 0.1f) * inv;
    py = (lp[1] + 0.1f) * inv;
  }

  f32x4 acc[2][2] = {};

  for (int k0 = 0; k0 < ND; k0 += 64) {
    {  // A-tile staging (heads fp16, L2-resident)
      const int o = o0 + sr;
      uint4 u0 = {0, 0, 0, 0}, u1 = {0, 0, 0, 0};
      if (o < NO) {
        const uint4* p = reinterpret_cast<const uint4*>(hh + (size_t)o * ND + k0 + sk);
        u0 = p[0]; u1 = p[1];
      }
      *reinterpret_cast<uint4*>(&As[sr][sk]) = u0;
      *reinterpret_cast<uint4*>(&As[sr][sk + 8]) = u1;
    }
    {  // B-tile generation: 16 consecutive k share i; base + py*s walks j.
      const int kg = k0 + sk;      // multiple of 16
      const int dd = kg & 1023;    // multiple of 16
      const float base = px * (float)(dd >> 5) + py * (float)(dd & 31)
                       + ((kg < 1024) ? 0.0f : 0.25f);
      f16x8 h0, h1;
#pragma unroll
      for (int s = 0; s < 8; ++s) {
        float ph = base + py * (float)s;
        ph -= floorf(ph);
        h0[s] = (_Float16)__builtin_amdgcn_sinf(ph);
      }
#pragma unroll
      for (int s = 0; s < 8; ++s) {
        float ph = base + py * (float)(s + 8);
        ph -= floorf(ph);
        h1[s] = (_Float16)__builtin_amdgcn_sinf(ph);
      }
      *reinterpret_cast<f16x8*>(&Bs[sr][sk]) = h0;
      *reinterpret_cast<f16x8*>(&Bs[sr][sk + 8]) = h1;
    }
    __syncthreads();
#pragma unroll
    for (int ks = 0; ks < 64; ks += 32) {
      const int kf = ks + quad * 8;
      const f16x8 a0 = *reinterpret_cast<const f16x8*>(&As[wm + ln][kf]);
      const f16x8 a1 = *reinterpret_cast<const f16x8*>(&As[wm + 16 + ln][kf]);
      const f16x8 b0 = *reinterpret_cast<const f16x8*>(&Bs[wn + ln][kf]);
      const f16x8 b1 = *reinterpret_cast<const f16x8*>(&Bs[wn + 16 + ln][kf]);
      acc[0][0] = __builtin_amdgcn_mfma_f32_16x16x32_f16(a0, b0, acc[0][0], 0, 0, 0);
      acc[0][1] = __builtin_amdgcn_mfma_f32_16x16x32_f16(a0, b1, acc[0][1], 0, 0, 0);
      acc[1][0] = __builtin_amdgcn_mfma_f32_16x16x32_f16(a1, b0, acc[1][0], 0, 0, 0);
      acc[1][1] = __builtin_amdgcn_mfma_f32_16x16x32_f16(a1, b1, acc[1][1], 0, 0, 0);
    }
    __syncthreads();
  }

  float* sB = scores + (size_t)b * NO * NC;
#pragma unroll
  for (int i = 0; i < 2; ++i) {
    const int ob = o0 + wm + 16 * i + quad * 4;
#pragma unroll
    for (int j = 0; j < 2; ++j) {
      const int cc = c0 + wn + 16 * j + ln;
      if (cc >= NC) continue;
#pragma unroll
      for (int r = 0; r < 4; ++r) {
        const int o = ob + r;
        if (o < NO) sB[(size_t)o * NC + cc] = acc[i][j][r];
      }
    }
  }
}

// ---------------------------------------------------------------------------
// Row softmax over C=273, fp32 in -> fp16 weights out, zero-padded to CP=288.
// One wave per (b,o) row. grid = 8640/4, block 256.
// ---------------------------------------------------------------------------
__global__ void softmax_kernel(const float* __restrict__ sc,
                               _Float16* __restrict__ wq) {
  const int row = blockIdx.x * 4 + (threadIdx.x >> 6);
  const int lane = threadIdx.x & 63;
  const float* p = sc + (size_t)row * NC;
  _Float16* q = wq + (size_t)row * CP;
  float v[5];
  float m = -3.0e38f;
#pragma unroll
  for (int k = 0; k < 5; ++k) {
    const int c = lane + k * 64;
    v[k] = (c < NC) ? p[c] : -3.0e38f;
    m = fmaxf(m, v[k]);
  }
#pragma unroll
  for (int off = 32; off > 0; off >>= 1) m = fmaxf(m, __shfl_xor(m, off));
  float s = 0.f;
#pragma unroll
  for (int k = 0; k < 5; ++k) {
    v[k] = expf(v[k] - m);
    s += v[k];
  }
#pragma unroll
  for (int off = 32; off > 0; off >>= 1) s += __shfl_xor(s, off);
  const float r = 1.0f / s;
#pragma unroll
  for (int k = 0; k < 5; ++k) {
    const int c = lane + k * 64;
    if (c < NC) q[c] = (_Float16)(v[k] * r);
    else if (c < CP) q[c] = (_Float16)0.f;
  }
}

// ---------------------------------------------------------------------------
// out[b,o,t] = sum_c W[b,o,c]*brain[b,c,t], brain read directly.
// Round-5 structure: K-chunk (32 c) staging pipelined against K-step MFMA,
// o-loop INSIDE (acc[5][2][2] per wave). Per iteration s:
//   issue A(s+1) W-frags (L2) + ds_write chunk s+1 (reg-staged, counted
//   vmcnt) + issue chunk s+3 brain loads + build B-frags from chunk s
//   (pitch-68, t XOR (row>>3)<<4 swizzle: writes min-phase, reads 2-way-free)
//   + raw s_barrier (lgkm-only drain, global loads stay in flight) + 20 MFMA.
// HBM demand is continuous across the whole block life; single store epilogue.
// LDS 17.4 KB; __launch_bounds__(256,2) -> 2 blocks/CU. grid = (47, 32).
// ---------------------------------------------------------------------------
__global__ __launch_bounds__(256, 2) void out_kernel(
    const _Float16* __restrict__ wq,
    const float* __restrict__ brain,
    float* __restrict__ out) {
  __shared__ float raw[2][32][68];
  const int b = blockIdx.y;
  const int t0 = blockIdx.x * 64;
  const int tid = threadIdx.x;
  const int lane = tid & 63, w = tid >> 6;
  const int om = (w >> 1) * 32, tn = (w & 1) * 32;
  const int ln = lane & 15, quad = lane >> 4;

  const _Float16* Wb = wq + (size_t)b * NO * CP;

  // staging thread mapping: 32 c-rows x (2 float4 at tq, tq+32)
  const int cl = tid >> 3;
  const int tq = (tid & 7) * 4;
  const int tb = t0 + tq;
  const int wsw = (cl >> 3) << 4;   // writer swizzle key (row bits 3-4)
  const int ws0 = tq ^ wsw;         // col slot for v0
  const int ws1 = (tq + 32) ^ wsw;  // col slot for v1

  // reader swizzled cols (row>>3 == quad for row = quad*8+j)
  const int rc0 = (tn + ln) ^ (quad << 4);
  const int rc1 = (tn + 16 + ln) ^ (quad << 4);

  auto load_chunk = [&](int ci, float4& v0, float4& v1) {
    float4 z = {0.f, 0.f, 0.f, 0.f};
    v0 = z; v1 = z;
    const int c = ci * 32 + cl;
    if (c < NC) {
      const float* src = brain + ((size_t)b * NC + c) * NT + tb;
      if (tb + 35 < NT) {
        v0 = *reinterpret_cast<const float4*>(src);
        v1 = *reinterpret_cast<const float4*>(src + 32);
      } else {
        if (tb + 0 < NT) v0.x = src[0];
        if (tb + 1 < NT) v0.y = src[1];
        if (tb + 2 < NT) v0.z = src[2];
        if (tb + 3 < NT) v0.w = src[3];
        if (tb + 32 < NT) v1.x = src[32];
        if (tb + 33 < NT) v1.y = src[33];
        if (tb + 34 < NT) v1.z = src[34];
        if (tb + 35 < NT) v1.w = src[35];
      }
    }
  };

  auto store_raw = [&](int buf, const float4& v0, const float4& v1) {
    *reinterpret_cast<float4*>(&raw[buf][cl][ws0]) = v0;
    *reinterpret_cast<float4*>(&raw[buf][cl][ws1]) = v1;
  };

  auto load_a = [&](int s, f16x8 (&a)[10]) {
    const int kcol = s * 32 + quad * 8;
#pragma unroll
    for (int ot = 0; ot < 5; ++ot) {
      int r0 = ot * 64 + om + ln;      if (r0 > NO - 1) r0 = NO - 1;
      int r1 = ot * 64 + om + 16 + ln; if (r1 > NO - 1) r1 = NO - 1;
      a[2 * ot]     = *reinterpret_cast<const f16x8*>(Wb + (size_t)r0 * CP + kcol);
      a[2 * ot + 1] = *reinterpret_cast<const f16x8*>(Wb + (size_t)r1 * CP + kcol);
    }
  };

  f32x4 acc[5][2][2] = {};

  auto do_mfma = [&](const f16x8 (&a)[10], f16x8 b0, f16x8 b1) {
#pragma unroll
    for (int ot = 0; ot < 5; ++ot) {
      acc[ot][0][0] = __builtin_amdgcn_mfma_f32_16x16x32_f16(a[2*ot],   b0, acc[ot][0][0], 0, 0, 0);
      acc[ot][0][1] = __builtin_amdgcn_mfma_f32_16x16x32_f16(a[2*ot],   b1, acc[ot][0][1], 0, 0, 0);
      acc[ot][1][0] = __builtin_amdgcn_mfma_f32_16x16x32_f16(a[2*ot+1], b0, acc[ot][1][0], 0, 0, 0);
      acc[ot][1][1] = __builtin_amdgcn_mfma_f32_16x16x32_f16(a[2*ot+1], b1, acc[ot][1][1], 0, 0, 0);
    }
  };

  f16x8 aE[10], aO[10];
  float4 rA0, rA1, rB0, rB1;  // even / odd chunk registers

  // ---- prologue: chunks 0..2 in flight, chunk 0 committed to LDS ----
  load_chunk(0, rA0, rA1);
  load_a(0, aE);
  load_chunk(1, rB0, rB1);
  store_raw(0, rA0, rA1);      // compiler waits (counted) on chunk-0 regs
  load_chunk(2, rA0, rA1);
  asm volatile("s_waitcnt lgkmcnt(0)" ::: "memory");
  __builtin_amdgcn_sched_barrier(0);
  __builtin_amdgcn_s_barrier();

#pragma unroll
  for (int s = 0; s < 9; ++s) {
    // issue next A-frags (L2) -- alternate register banks, zero copies
    if (s < 8) {
      if (((s + 1) & 1) == 0) load_a(s + 1, aE); else load_a(s + 1, aO);
    }
    // commit chunk s+1 to LDS (regs loaded 2 iters ago -> near-free wait),
    // then reuse the same regs for chunk s+3's loads
    if (s < 8) {
      if (((s + 1) & 1) == 0) {
        store_raw(0, rA0, rA1);
        if (s < 6) load_chunk(s + 3, rA0, rA1);
      } else {
        store_raw(1, rB0, rB1);
        if (s < 6) load_chunk(s + 3, rB0, rB1);
      }
    }
    // build B-frags from chunk s (2-way-free swizzled reads)
    f16x8 b0, b1;
    {
      const float* rb = &raw[s & 1][0][0];
#pragma unroll
      for (int j = 0; j < 8; ++j) {
        const int row = quad * 8 + j;
        b0[j] = (_Float16)rb[row * 68 + rc0];
        b1[j] = (_Float16)rb[row * 68 + rc1];
      }
    }
    if (s < 8) {
      asm volatile("s_waitcnt lgkmcnt(0)" ::: "memory");
      __builtin_amdgcn_sched_barrier(0);
      __builtin_amdgcn_s_barrier();
    }
    if ((s & 1) == 0) do_mfma(aE, b0, b1); else do_mfma(aO, b0, b1);
  }

  // ---- epilogue: single store pass ----
  float* oB = out + (size_t)b * NO * NT;
#pragma unroll
  for (int ot = 0; ot < 5; ++ot) {
#pragma unroll
    for (int i = 0; i < 2; ++i) {
      const int ob = ot * 64 + om + 16 * i + quad * 4;
#pragma unroll
      for (int j = 0; j < 2; ++j) {
        const int t = t0 + tn + 16 * j + ln;
        if (t >= NT) continue;
#pragma unroll
        for (int r = 0; r < 4; ++r) {
          const int o = ob + r;
          if (o < NO) oB[(size_t)o * NT + t] = acc[ot][i][j][r];
        }
      }
    }
  }
}

extern "C" void kernel_launch(void* const* d_in, const int* in_sizes, int n_in,
                              void* d_out, int out_size, void* d_ws, size_t ws_size,
                              hipStream_t stream) {
  const float* brain = (const float*)d_in[0];   // [32,273,3000]
  const float* layout = (const float*)d_in[1];  // [32,273,2]
  const float* heads = (const float*)d_in[2];   // [270,2048]
  for (int i = 0; i < n_in; ++i) {
    if (in_sizes[i] == NB * NC * NT) brain = (const float*)d_in[i];
    else if (in_sizes[i] == NB * NC * 2) layout = (const float*)d_in[i];
    else if (in_sizes[i] == NO * ND) heads = (const float*)d_in[i];
  }
  float* out = (float*)d_out;  // [32,270,3000]

  float* scores = (float*)((char*)d_ws + S_OFF);     // [NB][NO][NC]
  _Float16* wq = (_Float16*)((char*)d_ws + W_OFF);   // [NB][NO][CP]
  _Float16* hh = (_Float16*)((char*)d_ws + H_OFF);   // [NO][ND]

  heads_cvt_kernel<<<NO, 256, 0, stream>>>(heads, hh);
  scores_kernel<<<800, 256, 0, stream>>>(hh, layout, scores);
  softmax_kernel<<<(NB * NO) / 4, 256, 0, stream>>>(scores, wq);
  out_kernel<<<dim3(47, NB), 256, 0, stream>>>(wq, brain, out);
}

// Round 6
// 286.280 us; speedup vs baseline: 1.0145x; 1.0145x over previous
//
#include <hip/hip_runtime.h>
#include <hip/hip_bf16.h>
#include <hip/hip_fp16.h>

// SpatialAttention: B=32, C=273, T=3000, O=270, D=2048. fp32 in, fp32 out.
#define NB 32
#define NC 273
#define NT 3000
#define NO 270
#define ND 2048
#define CP 288  // C padded to 9*32 for out-GEMM K dimension

typedef _Float16 f16x8 __attribute__((ext_vector_type(8)));
typedef float f32x4 __attribute__((ext_vector_type(4)));

// Workspace layout (bytes):
//   [55296000, 64,730,880)  scores float   [NB][NO][NC]
//   [64730880, 69,707,520)  W     _Float16 [NB][NO][CP]  (softmaxed weights, zero-padded)
//   [69707520, 70,813,440)  headsh _Float16 [NO][ND]
#define S_OFF 55296000UL
#define W_OFF 64730880UL
#define H_OFF 69707520UL

// ---------------------------------------------------------------------------
// heads fp32 -> fp16. 270 blocks x 256 thr x 8 elems (exact).
// ---------------------------------------------------------------------------
__global__ void heads_cvt_kernel(const float* __restrict__ heads,
                                 _Float16* __restrict__ hh) {
  const size_t idx = ((size_t)blockIdx.x * 256 + threadIdx.x) * 8;
  const float4 a = *reinterpret_cast<const float4*>(heads + idx);
  const float4 c = *reinterpret_cast<const float4*>(heads + idx + 4);
  f16x8 v;
  v[0] = (_Float16)a.x; v[1] = (_Float16)a.y; v[2] = (_Float16)a.z; v[3] = (_Float16)a.w;
  v[4] = (_Float16)c.x; v[5] = (_Float16)c.y; v[6] = (_Float16)c.z; v[7] = (_Float16)c.w;
  *reinterpret_cast<f16x8*>(hh + idx) = v;
}

// ---------------------------------------------------------------------------
// scores[b,o,c] = sum_d heads[o,d]*emb[b,c,d], with the emb B-tile GENERATED
// in-register (phase naturally in revolutions -> fract + v_sin; cos folded
// as +0.25 rev). Tile 64(o) x 64(c), K-step 64, 4 waves 2x2.
// grid = 800 (5 c-tiles x 5 o-tiles x 32 b)
// ---------------------------------------------------------------------------
__global__ void scores_kernel(const _Float16* __restrict__ hh,
                              const float* __restrict__ layout,
                              float* __restrict__ scores) {
  __shared__ _Float16 As[64][72];
  __shared__ _Float16 Bs[64][72];
  const int gid = blockIdx.x;
  const int tid = threadIdx.x;
  const int b = gid / 25;
  const int rem = gid % 25;
  const int o0 = (rem / 5) * 64;
  const int c0 = (rem % 5) * 64;
  const int lane = tid & 63, w = tid >> 6;
  const int wm = (w >> 1) * 32, wn = (w & 1) * 32;
  const int ln = lane & 15, quad = lane >> 4;
  const int sr = tid >> 2;        // staging row 0..63 (o for A, c for B)
  const int sk = (tid & 3) * 16;  // k-chunk offset (halves)

  // Per-thread channel position for B-tile generation.
  const int ch = c0 + sr;
  float px = 0.f, py = 0.f;
  if (ch < NC) {
    const float inv = 1.0f / 1.2f;
    const float* lp = layout + ((size_t)b * NC + ch) * 2;
    px = (lp[0] + 0.1f) * inv;
    py = (lp[1] + 0.1f) * inv;
  }

  f32x4 acc[2][2] = {};

  for (int k0 = 0; k0 < ND; k0 += 64) {
    {  // A-tile staging (heads fp16, L2-resident)
      const int o = o0 + sr;
      uint4 u0 = {0, 0, 0, 0}, u1 = {0, 0, 0, 0};
      if (o < NO) {
        const uint4* p = reinterpret_cast<const uint4*>(hh + (size_t)o * ND + k0 + sk);
        u0 = p[0]; u1 = p[1];
      }
      *reinterpret_cast<uint4*>(&As[sr][sk]) = u0;
      *reinterpret_cast<uint4*>(&As[sr][sk + 8]) = u1;
    }
    {  // B-tile generation: 16 consecutive k share i; base + py*s walks j.
      const int kg = k0 + sk;      // multiple of 16
      const int dd = kg & 1023;    // multiple of 16
      const float base = px * (float)(dd >> 5) + py * (float)(dd & 31)
                       + ((kg < 1024) ? 0.0f : 0.25f);
      f16x8 h0, h1;
#pragma unroll
      for (int s = 0; s < 8; ++s) {
        float ph = base + py * (float)s;
        ph -= floorf(ph);
        h0[s] = (_Float16)__builtin_amdgcn_sinf(ph);
      }
#pragma unroll
      for (int s = 0; s < 8; ++s) {
        float ph = base + py * (float)(s + 8);
        ph -= floorf(ph);
        h1[s] = (_Float16)__builtin_amdgcn_sinf(ph);
      }
      *reinterpret_cast<f16x8*>(&Bs[sr][sk]) = h0;
      *reinterpret_cast<f16x8*>(&Bs[sr][sk + 8]) = h1;
    }
    __syncthreads();
#pragma unroll
    for (int ks = 0; ks < 64; ks += 32) {
      const int kf = ks + quad * 8;
      const f16x8 a0 = *reinterpret_cast<const f16x8*>(&As[wm + ln][kf]);
      const f16x8 a1 = *reinterpret_cast<const f16x8*>(&As[wm + 16 + ln][kf]);
      const f16x8 b0 = *reinterpret_cast<const f16x8*>(&Bs[wn + ln][kf]);
      const f16x8 b1 = *reinterpret_cast<const f16x8*>(&Bs[wn + 16 + ln][kf]);
      acc[0][0] = __builtin_amdgcn_mfma_f32_16x16x32_f16(a0, b0, acc[0][0], 0, 0, 0);
      acc[0][1] = __builtin_amdgcn_mfma_f32_16x16x32_f16(a0, b1, acc[0][1], 0, 0, 0);
      acc[1][0] = __builtin_amdgcn_mfma_f32_16x16x32_f16(a1, b0, acc[1][0], 0, 0, 0);
      acc[1][1] = __builtin_amdgcn_mfma_f32_16x16x32_f16(a1, b1, acc[1][1], 0, 0, 0);
    }
    __syncthreads();
  }

  float* sB = scores + (size_t)b * NO * NC;
#pragma unroll
  for (int i = 0; i < 2; ++i) {
    const int ob = o0 + wm + 16 * i + quad * 4;
#pragma unroll
    for (int j = 0; j < 2; ++j) {
      const int cc = c0 + wn + 16 * j + ln;
      if (cc >= NC) continue;
#pragma unroll
      for (int r = 0; r < 4; ++r) {
        const int o = ob + r;
        if (o < NO) sB[(size_t)o * NC + cc] = acc[i][j][r];
      }
    }
  }
}

// ---------------------------------------------------------------------------
// Row softmax over C=273, fp32 in -> fp16 weights out, zero-padded to CP=288.
// One wave per (b,o) row. grid = 8640/4, block 256.
// ---------------------------------------------------------------------------
__global__ void softmax_kernel(const float* __restrict__ sc,
                               _Float16* __restrict__ wq) {
  const int row = blockIdx.x * 4 + (threadIdx.x >> 6);
  const int lane = threadIdx.x & 63;
  const float* p = sc + (size_t)row * NC;
  _Float16* q = wq + (size_t)row * CP;
  float v[5];
  float m = -3.0e38f;
#pragma unroll
  for (int k = 0; k < 5; ++k) {
    const int c = lane + k * 64;
    v[k] = (c < NC) ? p[c] : -3.0e38f;
    m = fmaxf(m, v[k]);
  }
#pragma unroll
  for (int off = 32; off > 0; off >>= 1) m = fmaxf(m, __shfl_xor(m, off));
  float s = 0.f;
#pragma unroll
  for (int k = 0; k < 5; ++k) {
    v[k] = expf(v[k] - m);
    s += v[k];
  }
#pragma unroll
  for (int off = 32; off > 0; off >>= 1) s += __shfl_xor(s, off);
  const float r = 1.0f / s;
#pragma unroll
  for (int k = 0; k < 5; ++k) {
    const int c = lane + k * 64;
    if (c < NC) q[c] = (_Float16)(v[k] * r);
    else if (c < CP) q[c] = (_Float16)0.f;
  }
}

// ---------------------------------------------------------------------------
// out[b,o,t] = sum_c W[b,o,c]*brain[b,c,t], brain read DIRECTLY.
// Round-6 structure (anti-lockstep): stage the WHOLE [273][64] f32 slab with
// 17 wave-level global_load_lds issues (all independent -> ~70 KB in flight
// per block), ONE vmcnt(0)+barrier, then a compute phase with ZERO barriers.
// LDS is lane-linear [c][64] f32 (gload_lds can't scatter). Bank fix per
// rule #21: pre-swizzle the per-lane GLOBAL source (slot (c,g) holds t-group
// g ^ (qc<<1), qc=(c>>3)&3) and read at float col t ^ (qc<<3). Reader quad
// == qc for every fragment row -> banks ln ^ (quad<<3) = 2-way (free).
// Rows 273-287 zeroed (NaN-safety: A-side zeros don't kill B-side garbage);
// row 272 staged manually (guarded). t>=3000 garbage stays in its own MFMA
// column; stores are guarded. A-frags from L2-resident W[b] in registers,
// double-banked. LDS 73728 B -> 2 blocks/CU. grid = (47 t-slabs, 32 b).
// ---------------------------------------------------------------------------
__global__ __launch_bounds__(256, 2) void out_kernel(
    const _Float16* __restrict__ wq,
    const float* __restrict__ brain,
    float* __restrict__ out) {
  __shared__ float Bs[CP * 64];  // [c][64] f32, source-swizzled; 73728 B
  const int b = blockIdx.y;
  const int t0 = blockIdx.x * 64;
  const int tid = threadIdx.x;
  const int lane = tid & 63, w = tid >> 6;
  const int om = (w >> 1) * 32, tn = (w & 1) * 32;
  const int ln = lane & 15, quad = lane >> 4;

  const _Float16* Wb = wq + (size_t)b * NO * CP;

  auto load_a = [&](int s, f16x8 (&a)[10]) {
    const int kcol = s * 32 + quad * 8;
#pragma unroll
    for (int ot = 0; ot < 5; ++ot) {
      int r0 = ot * 64 + om + ln;      if (r0 > NO - 1) r0 = NO - 1;
      int r1 = ot * 64 + om + 16 + ln; if (r1 > NO - 1) r1 = NO - 1;
      a[2 * ot]     = *reinterpret_cast<const f16x8*>(Wb + (size_t)r0 * CP + kcol);
      a[2 * ot + 1] = *reinterpret_cast<const f16x8*>(Wb + (size_t)r1 * CP + kcol);
    }
  };

  f16x8 aE[10], aO[10];
  load_a(0, aE);  // in flight during staging (register dest, independent of LDS)

  // ---- stage rows 0..271: 17 passes of 4096 B, all issued back-to-back ----
  {
    const int g16 = tid & 15;                 // 16B-group within a 256B row
    const int crow = tid >> 4;                // row within a 16-row pass
    const float* gb = brain + (size_t)b * NC * NT + t0;
#pragma unroll
    for (int p = 0; p < 17; ++p) {
      const int c = p * 16 + crow;
      const int qc = (c >> 3) & 3;
      const float* gptr = gb + (size_t)c * NT + 4 * (g16 ^ (qc << 1));
      __builtin_amdgcn_global_load_lds(
          (const __attribute__((address_space(1))) void*)gptr,
          (__attribute__((address_space(3))) void*)(Bs + p * 1024 + w * 256),
          16, 0, 0);
    }
  }
  // row 272 (qc = 2), guarded manual stage
  if (tid < 16) {
    const float* src = brain + ((size_t)b * NC + 272) * NT + t0;
    const int toff = 4 * (tid ^ 4);
    float4 v = {0.f, 0.f, 0.f, 0.f};
    if (t0 + toff + 3 < NT) {
      v = *reinterpret_cast<const float4*>(src + toff);
    } else {
      if (t0 + toff + 0 < NT) v.x = src[toff + 0];
      if (t0 + toff + 1 < NT) v.y = src[toff + 1];
      if (t0 + toff + 2 < NT) v.z = src[toff + 2];
    }
    *reinterpret_cast<float4*>(Bs + 272 * 64 + tid * 4) = v;
  }
  // zero-pad rows 273..287 (15 rows x 256 B = 240 x 16 B)
  if (tid < 240) {
    const float4 z = {0.f, 0.f, 0.f, 0.f};
    *reinterpret_cast<float4*>(Bs + 273 * 64 + tid * 4) = z;
  }
  asm volatile("s_waitcnt vmcnt(0) lgkmcnt(0)" ::: "memory");
  __syncthreads();

  // ---- compute: 9 K-steps x 5 o-tiles, NO barriers ----
  const int rc0 = (tn + ln) ^ (quad << 3);       // swizzled float col (b0)
  const int rc1 = (tn + 16 + ln) ^ (quad << 3);  // swizzled float col (b1)
  f32x4 acc[5][2][2] = {};

  auto do_mfma = [&](const f16x8 (&a)[10], f16x8 b0, f16x8 b1) {
#pragma unroll
    for (int ot = 0; ot < 5; ++ot) {
      acc[ot][0][0] = __builtin_amdgcn_mfma_f32_16x16x32_f16(a[2*ot],   b0, acc[ot][0][0], 0, 0, 0);
      acc[ot][0][1] = __builtin_amdgcn_mfma_f32_16x16x32_f16(a[2*ot],   b1, acc[ot][0][1], 0, 0, 0);
      acc[ot][1][0] = __builtin_amdgcn_mfma_f32_16x16x32_f16(a[2*ot+1], b0, acc[ot][1][0], 0, 0, 0);
      acc[ot][1][1] = __builtin_amdgcn_mfma_f32_16x16x32_f16(a[2*ot+1], b1, acc[ot][1][1], 0, 0, 0);
    }
  };

#pragma unroll
  for (int s = 0; s < 9; ++s) {
    if (s < 8) {
      if (((s + 1) & 1) == 0) load_a(s + 1, aE); else load_a(s + 1, aO);
    }
    f16x8 b0, b1;
#pragma unroll
    for (int j = 0; j < 8; ++j) {
      const int c = s * 32 + quad * 8 + j;  // (c>>3)&3 == quad for j<8
      b0[j] = (_Float16)Bs[c * 64 + rc0];
      b1[j] = (_Float16)Bs[c * 64 + rc1];
    }
    if ((s & 1) == 0) do_mfma(aE, b0, b1); else do_mfma(aO, b0, b1);
  }

  // ---- epilogue: single store pass (full 64B lines per quad) ----
  float* oB = out + (size_t)b * NO * NT;
#pragma unroll
  for (int ot = 0; ot < 5; ++ot) {
#pragma unroll
    for (int i = 0; i < 2; ++i) {
      const int ob = ot * 64 + om + 16 * i + quad * 4;
#pragma unroll
      for (int j = 0; j < 2; ++j) {
        const int t = t0 + tn + 16 * j + ln;
        if (t >= NT) continue;
#pragma unroll
        for (int r = 0; r < 4; ++r) {
          const int o = ob + r;
          if (o < NO) oB[(size_t)o * NT + t] = acc[ot][i][j][r];
        }
      }
    }
  }
}

extern "C" void kernel_launch(void* const* d_in, const int* in_sizes, int n_in,
                              void* d_out, int out_size, void* d_ws, size_t ws_size,
                              hipStream_t stream) {
  const float* brain = (const float*)d_in[0];   // [32,273,3000]
  const float* layout = (const float*)d_in[1];  // [32,273,2]
  const float* heads = (const float*)d_in[2];   // [270,2048]
  for (int i = 0; i < n_in; ++i) {
    if (in_sizes[i] == NB * NC * NT) brain = (const float*)d_in[i];
    else if (in_sizes[i] == NB * NC * 2) layout = (const float*)d_in[i];
    else if (in_sizes[i] == NO * ND) heads = (const float*)d_in[i];
  }
  float* out = (float*)d_out;  // [32,270,3000]

  float* scores = (float*)((char*)d_ws + S_OFF);     // [NB][NO][NC]
  _Float16* wq = (_Float16*)((char*)d_ws + W_OFF);   // [NB][NO][CP]
  _Float16* hh = (_Float16*)((char*)d_ws + H_OFF);   // [NO][ND]

  heads_cvt_kernel<<<NO, 256, 0, stream>>>(heads, hh);
  scores_kernel<<<800, 256, 0, stream>>>(hh, layout, scores);
  softmax_kernel<<<(NB * NO) / 4, 256, 0, stream>>>(scores, wq);
  out_kernel<<<dim3(47, NB), 256, 0, stream>>>(wq, brain, out);
}

// Round 7
// 266.707 us; speedup vs baseline: 1.0890x; 1.0734x over previous
//
#include <hip/hip_runtime.h>
#include <hip/hip_bf16.h>
#include <hip/hip_fp16.h>

// SpatialAttention: B=32, C=273, T=3000, O=270, D=2048. fp32 in, fp32 out.
#define NB 32
#define NC 273
#define NT 3000
#define NO 270
#define ND 2048
#define CP 288  // C padded to 9*32 for out-GEMM K dimension

typedef _Float16 f16x8 __attribute__((ext_vector_type(8)));
typedef float f32x4 __attribute__((ext_vector_type(4)));

// Workspace layout (bytes):
//   [55296000, 64,730,880)  scores float   [NB][NO][NC]
//   [64730880, 69,707,520)  W     _Float16 [NB][NO][CP]  (softmaxed weights, zero-padded)
//   [69707520, 70,813,440)  headsh _Float16 [NO][ND]
#define S_OFF 55296000UL
#define W_OFF 64730880UL
#define H_OFF 69707520UL

__device__ __forceinline__ unsigned short f2h_bits(float f) {
  _Float16 h = (_Float16)f;
  unsigned short u;
  __builtin_memcpy(&u, &h, 2);
  return u;
}

// ---------------------------------------------------------------------------
// heads fp32 -> fp16. 270 blocks x 256 thr x 8 elems (exact).
// ---------------------------------------------------------------------------
__global__ void heads_cvt_kernel(const float* __restrict__ heads,
                                 _Float16* __restrict__ hh) {
  const size_t idx = ((size_t)blockIdx.x * 256 + threadIdx.x) * 8;
  const float4 a = *reinterpret_cast<const float4*>(heads + idx);
  const float4 c = *reinterpret_cast<const float4*>(heads + idx + 4);
  f16x8 v;
  v[0] = (_Float16)a.x; v[1] = (_Float16)a.y; v[2] = (_Float16)a.z; v[3] = (_Float16)a.w;
  v[4] = (_Float16)c.x; v[5] = (_Float16)c.y; v[6] = (_Float16)c.z; v[7] = (_Float16)c.w;
  *reinterpret_cast<f16x8*>(hh + idx) = v;
}

// ---------------------------------------------------------------------------
// scores[b,o,c] = sum_d heads[o,d]*emb[b,c,d], with the emb B-tile GENERATED
// in-register (phase naturally in revolutions -> fract + v_sin; cos folded
// as +0.25 rev). Tile 64(o) x 64(c), K-step 64, 4 waves 2x2.
// grid = 800 (5 c-tiles x 5 o-tiles x 32 b)
// ---------------------------------------------------------------------------
__global__ void scores_kernel(const _Float16* __restrict__ hh,
                              const float* __restrict__ layout,
                              float* __restrict__ scores) {
  __shared__ _Float16 As[64][72];
  __shared__ _Float16 Bs[64][72];
  const int gid = blockIdx.x;
  const int tid = threadIdx.x;
  const int b = gid / 25;
  const int rem = gid % 25;
  const int o0 = (rem / 5) * 64;
  const int c0 = (rem % 5) * 64;
  const int lane = tid & 63, w = tid >> 6;
  const int wm = (w >> 1) * 32, wn = (w & 1) * 32;
  const int ln = lane & 15, quad = lane >> 4;
  const int sr = tid >> 2;        // staging row 0..63 (o for A, c for B)
  const int sk = (tid & 3) * 16;  // k-chunk offset (halves)

  // Per-thread channel position for B-tile generation.
  const int ch = c0 + sr;
  float px = 0.f, py = 0.f;
  if (ch < NC) {
    const float inv = 1.0f / 1.2f;
    const float* lp = layout + ((size_t)b * NC + ch) * 2;
    px = (lp[0] + 0.1f) * inv;
    py = (lp[1] + 0.1f) * inv;
  }

  f32x4 acc[2][2] = {};

  for (int k0 = 0; k0 < ND; k0 += 64) {
    {  // A-tile staging (heads fp16, L2-resident)
      const int o = o0 + sr;
      uint4 u0 = {0, 0, 0, 0}, u1 = {0, 0, 0, 0};
      if (o < NO) {
        const uint4* p = reinterpret_cast<const uint4*>(hh + (size_t)o * ND + k0 + sk);
        u0 = p[0]; u1 = p[1];
      }
      *reinterpret_cast<uint4*>(&As[sr][sk]) = u0;
      *reinterpret_cast<uint4*>(&As[sr][sk + 8]) = u1;
    }
    {  // B-tile generation: 16 consecutive k share i; base + py*s walks j.
      const int kg = k0 + sk;      // multiple of 16
      const int dd = kg & 1023;    // multiple of 16
      const float base = px * (float)(dd >> 5) + py * (float)(dd & 31)
                       + ((kg < 1024) ? 0.0f : 0.25f);
      f16x8 h0, h1;
#pragma unroll
      for (int s = 0; s < 8; ++s) {
        float ph = base + py * (float)s;
        ph -= floorf(ph);
        h0[s] = (_Float16)__builtin_amdgcn_sinf(ph);
      }
#pragma unroll
      for (int s = 0; s < 8; ++s) {
        float ph = base + py * (float)(s + 8);
        ph -= floorf(ph);
        h1[s] = (_Float16)__builtin_amdgcn_sinf(ph);
      }
      *reinterpret_cast<f16x8*>(&Bs[sr][sk]) = h0;
      *reinterpret_cast<f16x8*>(&Bs[sr][sk + 8]) = h1;
    }
    __syncthreads();
#pragma unroll
    for (int ks = 0; ks < 64; ks += 32) {
      const int kf = ks + quad * 8;
      const f16x8 a0 = *reinterpret_cast<const f16x8*>(&As[wm + ln][kf]);
      const f16x8 a1 = *reinterpret_cast<const f16x8*>(&As[wm + 16 + ln][kf]);
      const f16x8 b0 = *reinterpret_cast<const f16x8*>(&Bs[wn + ln][kf]);
      const f16x8 b1 = *reinterpret_cast<const f16x8*>(&Bs[wn + 16 + ln][kf]);
      acc[0][0] = __builtin_amdgcn_mfma_f32_16x16x32_f16(a0, b0, acc[0][0], 0, 0, 0);
      acc[0][1] = __builtin_amdgcn_mfma_f32_16x16x32_f16(a0, b1, acc[0][1], 0, 0, 0);
      acc[1][0] = __builtin_amdgcn_mfma_f32_16x16x32_f16(a1, b0, acc[1][0], 0, 0, 0);
      acc[1][1] = __builtin_amdgcn_mfma_f32_16x16x32_f16(a1, b1, acc[1][1], 0, 0, 0);
    }
    __syncthreads();
  }

  float* sB = scores + (size_t)b * NO * NC;
#pragma unroll
  for (int i = 0; i < 2; ++i) {
    const int ob = o0 + wm + 16 * i + quad * 4;
#pragma unroll
    for (int j = 0; j < 2; ++j) {
      const int cc = c0 + wn + 16 * j + ln;
      if (cc >= NC) continue;
#pragma unroll
      for (int r = 0; r < 4; ++r) {
        const int o = ob + r;
        if (o < NO) sB[(size_t)o * NC + cc] = acc[i][j][r];
      }
    }
  }
}

// ---------------------------------------------------------------------------
// Row softmax over C=273, fp32 in -> fp16 weights out, zero-padded to CP=288.
// One wave per (b,o) row. grid = 8640/4, block 256.
// ---------------------------------------------------------------------------
__global__ void softmax_kernel(const float* __restrict__ sc,
                               _Float16* __restrict__ wq) {
  const int row = blockIdx.x * 4 + (threadIdx.x >> 6);
  const int lane = threadIdx.x & 63;
  const float* p = sc + (size_t)row * NC;
  _Float16* q = wq + (size_t)row * CP;
  float v[5];
  float m = -3.0e38f;
#pragma unroll
  for (int k = 0; k < 5; ++k) {
    const int c = lane + k * 64;
    v[k] = (c < NC) ? p[c] : -3.0e38f;
    m = fmaxf(m, v[k]);
  }
#pragma unroll
  for (int off = 32; off > 0; off >>= 1) m = fmaxf(m, __shfl_xor(m, off));
  float s = 0.f;
#pragma unroll
  for (int k = 0; k < 5; ++k) {
    v[k] = expf(v[k] - m);
    s += v[k];
  }
#pragma unroll
  for (int off = 32; off > 0; off >>= 1) s += __shfl_xor(s, off);
  const float r = 1.0f / s;
#pragma unroll
  for (int k = 0; k < 5; ++k) {
    const int c = lane + k * 64;
    if (c < NC) q[c] = (_Float16)(v[k] * r);
    else if (c < CP) q[c] = (_Float16)0.f;
  }
}

// ---------------------------------------------------------------------------
// out[b,o,t] = sum_c W[b,o,c]*brain[b,c,t], brain read DIRECTLY.
// Round-7: DRAM-GRANULE fix. Previous rounds read brain / wrote out in 256 B
// runs at 12 KB stride -> ~2 TB/s row-activation ceiling (4 structures, same
// wall). This version: TS=192 -> 768 B runs, whole slab fp16-resident in LDS
// (288 x 192 x 2 = 110.6 KB), brain read once, free-run compute (one barrier).
//   * grid = 512 blocks (16 t-slabs x 32 b) = exactly 2 balanced rounds.
//   * block = 512 thr (8 waves, 4(o-stripe) x 2(t-stripe)); acc[5][6]=120
//     VGPR/lane keeps 2 waves/SIMD (<=256 VGPR) -- why TS can't be 384.
//   * stage: 26 float4 loads/thread fully unrolled (216 KB/block in flight,
//     row-ordered streaming), cvt fp16, swizzled ds_write (col4 ^= qc<<4).
//   * reader t ^= quad<<4: quads hit disjoint 8-bank groups -> 0 conflicts.
//   * XCD-clustered decode: b = (flat&7)*4 + ((flat>>3)&3) -> each XCD owns
//     4 b's: W L2-resident per XCD, disjoint brain/out streams.
// ---------------------------------------------------------------------------
#define TS 192

__global__ __launch_bounds__(512, 2) void out_kernel(
    const _Float16* __restrict__ wq,
    const float* __restrict__ brain,
    float* __restrict__ out) {
  __shared__ _Float16 SB[CP * TS];  // [c][192] fp16, col-swizzled; 110592 B
  const int flat = blockIdx.x;
  const int b = (flat & 7) * 4 + ((flat >> 3) & 3);
  const int t0 = (flat >> 5) * TS;
  const int tid = threadIdx.x;

  // ---- stage: whole [273][192] slab, one burst ----
  {
    float4 vbuf[26];
#pragma unroll
    for (int p = 0; p < 26; ++p) {
      const int idx = p * 512 + tid;
      const int c = idx / 48, g = idx % 48;
      float4 v = {0.f, 0.f, 0.f, 0.f};
      if (c < NC) {
        int toff = t0 + 4 * g;
        if (toff > NT - 4) toff = NT - 4;  // tail slab: in-row clamp
        v = *reinterpret_cast<const float4*>(brain + ((size_t)b * NC + c) * NT + toff);
      }
      vbuf[p] = v;
    }
    // zero-pad rows 273..287 (2880 halves = 360 x 16 B)
    if (tid < 360) {
      const uint4 z = {0, 0, 0, 0};
      *reinterpret_cast<uint4*>(&SB[NC * TS + tid * 8]) = z;
    }
#pragma unroll
    for (int p = 0; p < 26; ++p) {
      const int idx = p * 512 + tid;
      const int c = idx / 48, g = idx % 48;
      if (c < NC) {
        const int qc = (c >> 3) & 3;
        const int h = c * TS + ((4 * g) ^ (qc << 4));
        uint2 u;
        u.x = (unsigned)f2h_bits(vbuf[p].x) | ((unsigned)f2h_bits(vbuf[p].y) << 16);
        u.y = (unsigned)f2h_bits(vbuf[p].z) | ((unsigned)f2h_bits(vbuf[p].w) << 16);
        *reinterpret_cast<uint2*>(&SB[h]) = u;
      }
    }
  }
  __syncthreads();  // slab ready; LDS read-only from here -> free-run

  const int w = tid >> 6, lane = tid & 63;
  const int ln = lane & 15, quad = lane >> 4;
  const int wm = (w >> 1) * 80;   // o-stripe: 4 stripes x 80 rows = 320
  const int wn = (w & 1) * 96;    // t-stripe: 2 stripes x 96 cols = 192
  const _Float16* Wb = wq + (size_t)b * NO * CP;

  f32x4 acc[5][6] = {};
  f16x8 afA[5], afB[5];

  auto load_af = [&](int s, f16x8 (&af)[5]) {
    const int col = s * 32 + quad * 8;
#pragma unroll
    for (int i = 0; i < 5; ++i) {
      int o = wm + i * 16 + ln;
      if (o > NO - 1) o = NO - 1;  // dup row 269; outputs discarded
      af[i] = *reinterpret_cast<const f16x8*>(Wb + (size_t)o * CP + col);
    }
  };

  load_af(0, afA);
#pragma unroll
  for (int s = 0; s < 9; ++s) {
    if (s < 8) {
      if (s & 1) load_af(s + 1, afA); else load_af(s + 1, afB);
    }
    f16x8 bf[6];
#pragma unroll
    for (int nf = 0; nf < 6; ++nf) {
      const int tsw = (wn + nf * 16 + ln) ^ (quad << 4);
#pragma unroll
      for (int j = 0; j < 8; ++j) {
        const int c = s * 32 + quad * 8 + j;
        bf[nf][j] = SB[c * TS + tsw];
      }
    }
    const f16x8(&af)[5] = (s & 1) ? afB : afA;
#pragma unroll
    for (int i = 0; i < 5; ++i) {
#pragma unroll
      for (int nf = 0; nf < 6; ++nf) {
        acc[i][nf] = __builtin_amdgcn_mfma_f32_16x16x32_f16(af[i], bf[nf], acc[i][nf], 0, 0, 0);
      }
    }
  }

  // ---- epilogue: 768 B per o-row per block ----
  float* oB = out + (size_t)b * NO * NT;
#pragma unroll
  for (int i = 0; i < 5; ++i) {
#pragma unroll
    for (int nf = 0; nf < 6; ++nf) {
      const int t = t0 + wn + nf * 16 + ln;
      if (t >= NT) continue;
#pragma unroll
      for (int r = 0; r < 4; ++r) {
        const int o = wm + i * 16 + quad * 4 + r;
        if (o < NO) oB[(size_t)o * NT + t] = acc[i][nf][r];
      }
    }
  }
}

extern "C" void kernel_launch(void* const* d_in, const int* in_sizes, int n_in,
                              void* d_out, int out_size, void* d_ws, size_t ws_size,
                              hipStream_t stream) {
  const float* brain = (const float*)d_in[0];   // [32,273,3000]
  const float* layout = (const float*)d_in[1];  // [32,273,2]
  const float* heads = (const float*)d_in[2];   // [270,2048]
  for (int i = 0; i < n_in; ++i) {
    if (in_sizes[i] == NB * NC * NT) brain = (const float*)d_in[i];
    else if (in_sizes[i] == NB * NC * 2) layout = (const float*)d_in[i];
    else if (in_sizes[i] == NO * ND) heads = (const float*)d_in[i];
  }
  float* out = (float*)d_out;  // [32,270,3000]

  float* scores = (float*)((char*)d_ws + S_OFF);     // [NB][NO][NC]
  _Float16* wq = (_Float16*)((char*)d_ws + W_OFF);   // [NB][NO][CP]
  _Float16* hh = (_Float16*)((char*)d_ws + H_OFF);   // [NO][ND]

  heads_cvt_kernel<<<NO, 256, 0, stream>>>(heads, hh);
  scores_kernel<<<800, 256, 0, stream>>>(hh, layout, scores);
  softmax_kernel<<<(NB * NO) / 4, 256, 0, stream>>>(scores, wq);
  out_kernel<<<512, 512, 0, stream>>>(wq, brain, out);
}